// Round 1
// baseline (14707.805 us; speedup 1.0000x reference)
//
#include <hip/hip_runtime.h>

#define T_STEPS 512
#define BATCH   64
#define HID     1024
#define GDIM    4096   // 4*H gate columns
#define KDIM    2048   // [h | x] fused K
#define NWG     128    // persistent workgroups (1 per CU, LDS-bound)
#define CWG     32     // gate columns per wg (2 x 16-col MFMA tiles)

using short8  = __attribute__((ext_vector_type(8))) short;
using floatx4 = __attribute__((ext_vector_type(4))) float;

__device__ inline unsigned short bf16_rne(float f) {
  union { float f; unsigned u; } x; x.f = f;
  unsigned r = x.u + 0x7FFFu + ((x.u >> 16) & 1u);
  return (unsigned short)(r >> 16);
}

__device__ inline float sigmoid_(float x) { return 1.0f / (1.0f + __expf(-x)); }
__device__ inline float tanh_(float x) {
  float e = __expf(-2.0f * fabsf(x));
  float r = (1.0f - e) / (1.0f + e);
  return copysignf(r, x);
}

#define LOAD4(dst, ptr) { float4 _t4 = *(const float4*)(ptr); \
  dst[0]=_t4.x; dst[1]=_t4.y; dst[2]=_t4.z; dst[3]=_t4.w; }

// ---------------------------------------------------------------------------
// One-time per call: pack [W_hh | W_ih] into bf16 Wcat[4096][2048]
// ---------------------------------------------------------------------------
__global__ __launch_bounds__(256) void cvt_w_kernel(
    const float* __restrict__ w_hh, const float* __restrict__ w_ih,
    unsigned short* __restrict__ wcat)
{
  int idx  = blockIdx.x * 256 + threadIdx.x;   // one thread per 4 elems
  int base = idx * 4;
  int g = base >> 11;        // /2048
  int k = base & 2047;
  const float* src = (k < 1024) ? (w_hh + (size_t)g * 1024 + k)
                                : (w_ih + (size_t)g * 1024 + (k - 1024));
  float a = src[0], b = src[1], c = src[2], d = src[3];
  uint2 v;
  v.x = (unsigned)bf16_rne(a) | ((unsigned)bf16_rne(b) << 16);
  v.y = (unsigned)bf16_rne(c) | ((unsigned)bf16_rne(d) << 16);
  *(uint2*)(wcat + base) = v;
}

// ---------------------------------------------------------------------------
// One-time per call: h0, x0 -> bf16 side buffers; cell -> c_ws
// ---------------------------------------------------------------------------
__global__ __launch_bounds__(256) void init_kernel(
    const float* __restrict__ hidden, const float* __restrict__ x0,
    const float* __restrict__ cell,
    unsigned short* __restrict__ hbf, unsigned short* __restrict__ xbf,
    float* __restrict__ c_ws)
{
  const int b = blockIdx.x;
  const int j = threadIdx.x * 4;
  const size_t off = (size_t)b * HID + j;
  float4 h = *(const float4*)(hidden + off);
  float4 x = *(const float4*)(x0 + off);
  float4 c = *(const float4*)(cell + off);
  ushort4 hv, xv;
  hv.x = bf16_rne(h.x); hv.y = bf16_rne(h.y); hv.z = bf16_rne(h.z); hv.w = bf16_rne(h.w);
  xv.x = bf16_rne(x.x); xv.y = bf16_rne(x.y); xv.z = bf16_rne(x.z); xv.w = bf16_rne(x.w);
  *(ushort4*)(hbf + off) = hv;
  *(ushort4*)(xbf + off) = xv;
  *(float4*)(c_ws + off) = c;
}

// ---------------------------------------------------------------------------
// Device-scope producer/consumer sync.
// Release: __syncthreads drains each wave's stores to L2 (compiler emits
// vmcnt(0) before s_barrier); thread0's __threadfence (agent scope) emits
// buffer_wbl2 -> pushes XCD L2 to the coherence point; then the atomic add.
// Acquire: after the spin observes the target, __threadfence emits buffer_inv
// -> invalidates stale L1/L2 lines before any thread of the wg reads.
// ---------------------------------------------------------------------------
__device__ inline void wait_ge(unsigned* p, unsigned target) {
  if (threadIdx.x == 0) {
    while (__hip_atomic_load(p, __ATOMIC_RELAXED, __HIP_MEMORY_SCOPE_AGENT) < target)
      __builtin_amdgcn_s_sleep(2);
    __threadfence();                       // acquire
  }
  __syncthreads();
}

__device__ inline void arrive_(unsigned* p) {
  __syncthreads();                         // all block stores drained
  if (threadIdx.x == 0) {
    __threadfence();                       // release
    __hip_atomic_fetch_add(p, 1u, __ATOMIC_RELAXED, __HIP_MEMORY_SCOPE_AGENT);
  }
}

// ---------------------------------------------------------------------------
// block reduce: sum N accumulators across 256 threads (4 waves of 64)
// ---------------------------------------------------------------------------
template<int N>
__device__ inline void block_reduce(float* v, float* red, int tid) {
#pragma unroll
  for (int i = 0; i < N; ++i) {
    float x = v[i];
#pragma unroll
    for (int off = 32; off > 0; off >>= 1)
      x += __shfl_xor(x, off, 64);
    v[i] = x;
  }
  const int wave = tid >> 6;
  if ((tid & 63) == 0) {
#pragma unroll
    for (int i = 0; i < N; ++i) red[wave * N + i] = v[i];
  }
  __syncthreads();
#pragma unroll
  for (int i = 0; i < N; ++i)
    v[i] = red[i] + red[N + i] + red[2 * N + i] + red[3 * N + i];
}

// ---------------------------------------------------------------------------
// Persistent kernel: all 512 time steps in one launch.
// 128 wgs x 256 thr. Each wg owns 32 gate columns; its B tile (32 cols x
// 2048 K, bf16 fragment order) lives in LDS for the whole kernel (128 KiB
// -> 1 wg/CU, so all 128 wgs are co-resident and flag-sync is safe).
// Per step:
//   phase G (all wgs): gates[64][n0..n0+32] = [h|x]bf16 @ Wcat^T, arrive gcnt
//   phase S (wgs 0..63): wait gcnt, LN+pointwise for batch row wg, write
//     out/h(bf16)/c and x_{t+1}->bf16, arrive hcnt
//   next step's phase G waits hcnt.
// ---------------------------------------------------------------------------
__global__ __launch_bounds__(256, 1) void lstm_persist(
    const unsigned short* __restrict__ wcat,
    const float* __restrict__ input,
    float* __restrict__ gates, float* __restrict__ c_ws,
    const float* __restrict__ w_ch, const float* __restrict__ bias,
    const float* __restrict__ gamma_f, const float* __restrict__ gamma_i,
    const float* __restrict__ gamma_g, const float* __restrict__ gamma_o,
    const float* __restrict__ gamma_c, const float* __restrict__ beta_c,
    float* __restrict__ out,
    unsigned short* __restrict__ hbf, unsigned short* __restrict__ xbf,
    unsigned* __restrict__ syncp)
{
  __shared__ __align__(16) unsigned short smB[CWG * KDIM];  // 128 KiB, persistent W tile
  __shared__ float sm[40];

  const int wg   = blockIdx.x;
  const int tid  = threadIdx.x;
  const int wave = tid >> 6;
  const int lane = tid & 63;
  const int quad = lane >> 4;
  const int l16  = lane & 15;
  const int n0   = wg * CWG;

  unsigned* gcnt = syncp;        // gates ready: +1 per GEMM wg per step
  unsigned* hcnt = syncp + 64;   // h ready:    +1 per step wg per step

  // ---- one-time: stage B tile into LDS in MFMA-fragment order ----
  // frag idx = t2*64 + kc  (t2 = 16-col tile, kc = 32-wide K chunk)
  // frag(lane) = wcat[n0 + t2*16 + l16][kc*32 + quad*8 .. +8]
  for (int i = 0; i < 32; ++i) {
    int idx = wave * 32 + i;
    int t2 = idx >> 6, kc = idx & 63;
    short8 v = *(const short8*)(wcat + (size_t)(n0 + t2 * 16 + l16) * KDIM
                                + kc * 32 + quad * 8);
    *(short8*)(smB + (size_t)idx * 512 + lane * 8) = v;
  }
  __syncthreads();

  // A-frag pointers (m89-verified 16x16x32 layout: A[m=l16][k=quad*8+j])
  const unsigned short* arow_h = hbf + (size_t)(wave * 16 + l16) * HID + quad * 8;
  const unsigned short* arow_x = xbf + (size_t)(wave * 16 + l16) * HID + quad * 8;

  for (int t = 0; t < T_STEPS; ++t) {
    // h_t / x_t ready (t=0: trivially true, state from init_kernel)
    wait_ge(hcnt, 64u * (unsigned)t);

    floatx4 acc0 = {0, 0, 0, 0}, acc1 = {0, 0, 0, 0};

    // K = 0..1024 (h part)
#pragma unroll 8
    for (int kc = 0; kc < 32; ++kc) {
      short8 a  = *(const short8*)(arow_h + kc * 32);
      short8 b0 = *(const short8*)(smB + (size_t)kc * 512 + lane * 8);
      short8 b1 = *(const short8*)(smB + (size_t)(64 + kc) * 512 + lane * 8);
      acc0 = __builtin_amdgcn_mfma_f32_16x16x32_bf16(a, b0, acc0, 0, 0, 0);
      acc1 = __builtin_amdgcn_mfma_f32_16x16x32_bf16(a, b1, acc1, 0, 0, 0);
    }
    // K = 1024..2048 (x part)
#pragma unroll 8
    for (int kc = 0; kc < 32; ++kc) {
      short8 a  = *(const short8*)(arow_x + kc * 32);
      short8 b0 = *(const short8*)(smB + (size_t)(32 + kc) * 512 + lane * 8);
      short8 b1 = *(const short8*)(smB + (size_t)(96 + kc) * 512 + lane * 8);
      acc0 = __builtin_amdgcn_mfma_f32_16x16x32_bf16(a, b0, acc0, 0, 0, 0);
      acc1 = __builtin_amdgcn_mfma_f32_16x16x32_bf16(a, b1, acc1, 0, 0, 0);
    }

    // C/D layout (m89-verified): col = l16 (within tile), row = quad*4 + r
#pragma unroll
    for (int r = 0; r < 4; ++r) {
      int m = wave * 16 + quad * 4 + r;
      float* gm = gates + (size_t)m * GDIM + n0 + l16;
      gm[0]  = acc0[r];
      gm[16] = acc1[r];
    }
    arrive_(gcnt);

    if (wg < BATCH) {
      wait_ge(gcnt, 128u * (unsigned)(t + 1));

      const int b = wg;
      const int j = tid * 4;
      const float* grow = gates + (size_t)b * GDIM;

      float fh[4], ih[4], gh[4], oh[4], cc[4], wcf[4], wci[4], wco[4];
      LOAD4(fh, grow + j);
      LOAD4(ih, grow + HID + j);
      LOAD4(gh, grow + 2 * HID + j);
      LOAD4(oh, grow + 3 * HID + j);
      LOAD4(cc, c_ws + (size_t)b * HID + j);
      LOAD4(wcf, w_ch + j);
      LOAD4(wci, w_ch + HID + j);
      LOAD4(wco, w_ch + 2 * HID + j);

      // prefetch x_{t+1} early so the HBM latency hides under the LN math
      float4 xv;
      const int has_next = (t + 1 < T_STEPS);
      if (has_next)
        xv = *(const float4*)(input + (size_t)(t + 1) * BATCH * HID
                              + (size_t)b * HID + j);

      float af[4], ai[4], ag[4];
      float s[6] = {0, 0, 0, 0, 0, 0};
#pragma unroll
      for (int r = 0; r < 4; ++r) {
        af[r] = fh[r] + wcf[r] * cc[r];
        ai[r] = ih[r] + wci[r] * cc[r];
        ag[r] = gh[r];
        s[0] += af[r]; s[1] += af[r] * af[r];
        s[2] += ai[r]; s[3] += ai[r] * ai[r];
        s[4] += ag[r]; s[5] += ag[r] * ag[r];
      }
      block_reduce<6>(s, sm, tid);
      const float invH = 1.0f / (float)HID;
      float mu_f = s[0] * invH, is_f = rsqrtf(s[1] * invH - mu_f * mu_f + 1e-5f);
      float mu_i = s[2] * invH, is_i = rsqrtf(s[3] * invH - mu_i * mu_i + 1e-5f);
      float mu_g = s[4] * invH, is_g = rsqrtf(s[5] * invH - mu_g * mu_g + 1e-5f);

      float gf4[4], gi4[4], gg4[4], bf4[4], bi4[4], bg4[4];
      LOAD4(gf4, gamma_f + j); LOAD4(gi4, gamma_i + j); LOAD4(gg4, gamma_g + j);
      LOAD4(bf4, bias + j);    LOAD4(bi4, bias + HID + j); LOAD4(bg4, bias + 2 * HID + j);

      float cn[4], ao[4];
      float s2[4] = {0, 0, 0, 0};
#pragma unroll
      for (int r = 0; r < 4; ++r) {
        float f = sigmoid_((af[r] - mu_f) * is_f * gf4[r] + bf4[r]);
        float i = sigmoid_((ai[r] - mu_i) * is_i * gi4[r] + bi4[r]);
        float g = tanh_((ag[r] - mu_g) * is_g * gg4[r] + bg4[r]);
        cn[r] = f * cc[r] + i * g;
        ao[r] = oh[r] + wco[r] * cn[r];
        s2[0] += cn[r]; s2[1] += cn[r] * cn[r];
        s2[2] += ao[r]; s2[3] += ao[r] * ao[r];
      }
      { float4 tt; tt.x = cn[0]; tt.y = cn[1]; tt.z = cn[2]; tt.w = cn[3];
        *(float4*)(c_ws + (size_t)b * HID + j) = tt; }

      block_reduce<4>(s2, sm + 24, tid);
      float mu_c = s2[0] * invH, is_c = rsqrtf(s2[1] * invH - mu_c * mu_c + 1e-5f);
      float mu_o = s2[2] * invH, is_o = rsqrtf(s2[3] * invH - mu_o * mu_o + 1e-5f);

      float gc4[4], bc4[4], go4[4], bo4[4];
      LOAD4(gc4, gamma_c + j); LOAD4(bc4, beta_c + j);
      LOAD4(go4, gamma_o + j); LOAD4(bo4, bias + 3 * HID + j);

      float h4[4];
#pragma unroll
      for (int r = 0; r < 4; ++r) {
        float cl = (cn[r] - mu_c) * is_c * gc4[r] + bc4[r];
        float o  = sigmoid_((ao[r] - mu_o) * is_o * go4[r] + bo4[r]);
        h4[r] = o * tanh_(cl);
      }
      { float4 tt; tt.x = h4[0]; tt.y = h4[1]; tt.z = h4[2]; tt.w = h4[3];
        *(float4*)(out + (size_t)t * BATCH * HID + (size_t)b * HID + j) = tt; }
      { ushort4 hv;
        hv.x = bf16_rne(h4[0]); hv.y = bf16_rne(h4[1]);
        hv.z = bf16_rne(h4[2]); hv.w = bf16_rne(h4[3]);
        *(ushort4*)(hbf + (size_t)b * HID + j) = hv; }

      if (has_next) {
        ushort4 xb;
        xb.x = bf16_rne(xv.x); xb.y = bf16_rne(xv.y);
        xb.z = bf16_rne(xv.z); xb.w = bf16_rne(xv.w);
        *(ushort4*)(xbf + (size_t)b * HID + j) = xb;
      }
      arrive_(hcnt);
    }
  }
}

// ---------------------------------------------------------------------------
extern "C" void kernel_launch(void* const* d_in, const int* in_sizes, int n_in,
                              void* d_out, int out_size, void* d_ws, size_t ws_size,
                              hipStream_t stream) {
  (void)in_sizes; (void)n_in; (void)out_size; (void)ws_size;
  const float* input   = (const float*)d_in[0];
  const float* hidden  = (const float*)d_in[1];
  const float* cell    = (const float*)d_in[2];
  const float* w_ih    = (const float*)d_in[3];
  const float* w_hh    = (const float*)d_in[4];
  const float* w_ch    = (const float*)d_in[5];
  const float* bias    = (const float*)d_in[6];
  const float* gamma_f = (const float*)d_in[7];
  const float* gamma_i = (const float*)d_in[8];
  const float* gamma_g = (const float*)d_in[9];
  const float* gamma_o = (const float*)d_in[10];
  const float* gamma_c = (const float*)d_in[11];
  const float* beta_c  = (const float*)d_in[12];
  float* out = (float*)d_out;

  // ws: [ Wcat bf16 16MB | gates 1MB | c 256KB | hbf 128KB | xbf 128KB | sync 512B ]
  unsigned short* wcat = (unsigned short*)d_ws;
  float* gates = (float*)((char*)d_ws + (size_t)GDIM * KDIM * sizeof(unsigned short));
  float* c_ws  = gates + (size_t)BATCH * GDIM;
  unsigned short* hbf = (unsigned short*)(c_ws + BATCH * HID);
  unsigned short* xbf = hbf + BATCH * HID;
  unsigned* syncp = (unsigned*)(xbf + BATCH * HID);

  cvt_w_kernel<<<(GDIM * KDIM / 4) / 256, 256, 0, stream>>>(w_hh, w_ih, wcat);
  init_kernel<<<BATCH, 256, 0, stream>>>(hidden, input, cell, hbf, xbf, c_ws);
  hipMemsetAsync(syncp, 0, 512, stream);   // counters must be 0 on every graph replay

  lstm_persist<<<NWG, 256, 0, stream>>>(
      wcat, input, gates, c_ws, w_ch, bias, gamma_f, gamma_i, gamma_g,
      gamma_o, gamma_c, beta_c, out, hbf, xbf, syncp);

  const size_t OUT0 = (size_t)T_STEPS * BATCH * HID;
  hipMemcpyAsync(out + OUT0, out + (OUT0 - BATCH * HID),
                 (size_t)BATCH * HID * sizeof(float), hipMemcpyDeviceToDevice, stream);
  hipMemcpyAsync(out + OUT0 + BATCH * HID, c_ws,
                 (size_t)BATCH * HID * sizeof(float), hipMemcpyDeviceToDevice, stream);
}

// Round 2
// 10499.136 us; speedup vs baseline: 1.4009x; 1.4009x over previous
//
#include <hip/hip_runtime.h>

#define T_STEPS 512
#define BATCH   64
#define HID     1024
#define GDIM    4096   // 4*H gate columns
#define KDIM    2048   // [h | x] fused K
#define NWG     128    // persistent workgroups (1 per CU, LDS-bound)
#define CWG     32     // gate columns per wg (2 x 16-col MFMA tiles)

using short8  = __attribute__((ext_vector_type(8))) short;
using floatx4 = __attribute__((ext_vector_type(4))) float;
typedef unsigned long long u64;

__device__ inline unsigned short bf16_rne(float f) {
  union { float f; unsigned u; } x; x.f = f;
  unsigned r = x.u + 0x7FFFu + ((x.u >> 16) & 1u);
  return (unsigned short)(r >> 16);
}

__device__ inline float sigmoid_(float x) { return 1.0f / (1.0f + __expf(-x)); }
__device__ inline float tanh_(float x) {
  float e = __expf(-2.0f * fabsf(x));
  float r = (1.0f - e) / (1.0f + e);
  return copysignf(r, x);
}

#define LOAD4(dst, ptr) { float4 _t4 = *(const float4*)(ptr); \
  dst[0]=_t4.x; dst[1]=_t4.y; dst[2]=_t4.z; dst[3]=_t4.w; }

// ---------------------------------------------------------------------------
// MALL-coherent primitives: relaxed agent-scope atomics -> sc0|sc1 cache-
// bypass loads/stores, NO fences, fully pipelinable. Data lands at / is read
// from the coherence point (Infinity Cache), so no L2 wb/inv is ever needed.
// ---------------------------------------------------------------------------
__device__ inline u64 ld_u64_mall(const void* p) {
  return __hip_atomic_load((const u64*)p, __ATOMIC_RELAXED, __HIP_MEMORY_SCOPE_AGENT);
}
__device__ inline void st_u64_mall(void* p, u64 v) {
  __hip_atomic_store((u64*)p, v, __ATOMIC_RELAXED, __HIP_MEMORY_SCOPE_AGENT);
}
__device__ inline void st_u32_mall(void* p, unsigned v) {
  __hip_atomic_store((unsigned*)p, v, __ATOMIC_RELAXED, __HIP_MEMORY_SCOPE_AGENT);
}
__device__ inline short8 ld_a16_mall(const unsigned short* p) {
  union { u64 q[2]; short8 v; } u;
  u.q[0] = ld_u64_mall(p);
  u.q[1] = ld_u64_mall(p + 4);
  return u.v;
}
__device__ inline void ld4f_mall(float* d, const float* p) {
  union { u64 q; float f[2]; } a, b;
  a.q = ld_u64_mall(p);
  b.q = ld_u64_mall(p + 2);
  d[0] = a.f[0]; d[1] = a.f[1]; d[2] = b.f[0]; d[3] = b.f[1];
}
__device__ inline void st4h_mall(unsigned short* p, float a, float b, float c, float d) {
  union { u64 q; unsigned short s[4]; } u;
  u.s[0] = bf16_rne(a); u.s[1] = bf16_rne(b); u.s[2] = bf16_rne(c); u.s[3] = bf16_rne(d);
  st_u64_mall(p, u.q);
}

// ---------------------------------------------------------------------------
// Lightweight producer/consumer sync. NO cache maintenance:
//  arrive: per-wave vmcnt(0) (all bypass-stores complete AT MALL) -> barrier
//          -> one relaxed atomic add at MALL.
//  wait:   lane0 relaxed spin (s_sleep backoff) -> barrier -> compiler fence.
// Consumers read either via bypass loads (always coherent) or via normal
// loads at never-before-seen addresses (pool mode) -> no staleness possible.
// ---------------------------------------------------------------------------
__device__ inline void wait_ge(unsigned* p, unsigned target) {
  if (threadIdx.x == 0) {
    while (__hip_atomic_load(p, __ATOMIC_RELAXED, __HIP_MEMORY_SCOPE_AGENT) < target)
      __builtin_amdgcn_s_sleep(4);
  }
  __syncthreads();
  asm volatile("" ::: "memory");
}
__device__ inline void arrive_(unsigned* p) {
  asm volatile("s_waitcnt vmcnt(0)" ::: "memory");  // every wave drains its stores
  __syncthreads();
  if (threadIdx.x == 0)
    __hip_atomic_fetch_add(p, 1u, __ATOMIC_RELAXED, __HIP_MEMORY_SCOPE_AGENT);
}

// ---------------------------------------------------------------------------
// One-time: pack [W_hh | W_ih] into bf16 Wcat[4096][2048]
// ---------------------------------------------------------------------------
__global__ __launch_bounds__(256) void cvt_w_kernel(
    const float* __restrict__ w_hh, const float* __restrict__ w_ih,
    unsigned short* __restrict__ wcat)
{
  int idx  = blockIdx.x * 256 + threadIdx.x;
  int base = idx * 4;
  int g = base >> 11;
  int k = base & 2047;
  const float* src = (k < 1024) ? (w_hh + (size_t)g * 1024 + k)
                                : (w_ih + (size_t)g * 1024 + (k - 1024));
  float a = src[0], b = src[1], c = src[2], d = src[3];
  uint2 v;
  v.x = (unsigned)bf16_rne(a) | ((unsigned)bf16_rne(b) << 16);
  v.y = (unsigned)bf16_rne(c) | ((unsigned)bf16_rne(d) << 16);
  *(uint2*)(wcat + base) = v;
}

// ---------------------------------------------------------------------------
// One-time (pool mode): convert the whole input stream to bf16 (read-only
// thereafter -> consumers may use normal cached loads, shared within XCD L2)
// ---------------------------------------------------------------------------
__global__ __launch_bounds__(256) void cvt_x_kernel(
    const float* __restrict__ x, unsigned short* __restrict__ xall)
{
  size_t i = ((size_t)blockIdx.x * 256 + threadIdx.x) * 8;
  float4 a = *(const float4*)(x + i);
  float4 b = *(const float4*)(x + i + 4);
  union { unsigned short s[8]; uint4 v; } u;
  u.s[0] = bf16_rne(a.x); u.s[1] = bf16_rne(a.y); u.s[2] = bf16_rne(a.z); u.s[3] = bf16_rne(a.w);
  u.s[4] = bf16_rne(b.x); u.s[5] = bf16_rne(b.y); u.s[6] = bf16_rne(b.z); u.s[7] = bf16_rne(b.w);
  *(uint4*)(xall + i) = u.v;
}

// ---------------------------------------------------------------------------
// One-time: h0 -> bf16 (pool slot 0 or single buffer), x0 -> bf16, cell -> c_ws
// ---------------------------------------------------------------------------
__global__ __launch_bounds__(256) void init_kernel(
    const float* __restrict__ hidden, const float* __restrict__ x0,
    const float* __restrict__ cell,
    unsigned short* __restrict__ hdst, unsigned short* __restrict__ xdst,
    float* __restrict__ c_ws)
{
  const int b = blockIdx.x;
  const int j = threadIdx.x * 4;
  const size_t off = (size_t)b * HID + j;
  float4 h = *(const float4*)(hidden + off);
  float4 x = *(const float4*)(x0 + off);
  float4 c = *(const float4*)(cell + off);
  ushort4 hv, xv;
  hv.x = bf16_rne(h.x); hv.y = bf16_rne(h.y); hv.z = bf16_rne(h.z); hv.w = bf16_rne(h.w);
  xv.x = bf16_rne(x.x); xv.y = bf16_rne(x.y); xv.z = bf16_rne(x.z); xv.w = bf16_rne(x.w);
  *(ushort4*)(hdst + off) = hv;
  *(ushort4*)(xdst + off) = xv;
  *(float4*)(c_ws + off) = c;
}

// ---------------------------------------------------------------------------
template<int N>
__device__ inline void block_reduce(float* v, float* red, int tid) {
#pragma unroll
  for (int i = 0; i < N; ++i) {
    float x = v[i];
#pragma unroll
    for (int off = 32; off > 0; off >>= 1)
      x += __shfl_xor(x, off, 64);
    v[i] = x;
  }
  const int wave = tid >> 6;
  if ((tid & 63) == 0) {
#pragma unroll
    for (int i = 0; i < N; ++i) red[wave * N + i] = v[i];
  }
  __syncthreads();
#pragma unroll
  for (int i = 0; i < N; ++i)
    v[i] = red[i] + red[N + i] + red[2 * N + i] + red[3 * N + i];
}

// ---------------------------------------------------------------------------
// Persistent kernel, POOL=1: h_t -> fresh pool slot per step (normal cached
// reads, XCD-shared), x pre-converted; POOL=0: single h/x buffers, all
// cross-wg data via MALL-bypass atomics.
// ---------------------------------------------------------------------------
template<int POOL>
__global__ __launch_bounds__(256, 1) void lstm_persist(
    const unsigned short* __restrict__ wcat,
    const float* __restrict__ input,
    float* __restrict__ gates, float* __restrict__ c_ws,
    const float* __restrict__ w_ch, const float* __restrict__ bias,
    const float* __restrict__ gamma_f, const float* __restrict__ gamma_i,
    const float* __restrict__ gamma_g, const float* __restrict__ gamma_o,
    const float* __restrict__ gamma_c, const float* __restrict__ beta_c,
    float* __restrict__ out,
    unsigned short* __restrict__ hA,   // POOL: 512-slot pool; else single buf
    unsigned short* __restrict__ xA,   // POOL: xall (all t);  else single buf
    unsigned* __restrict__ syncp)
{
  __shared__ __align__(16) unsigned short smB[CWG * KDIM];  // 128 KiB W tile
  __shared__ float sm[40];

  const int wg   = blockIdx.x;
  const int tid  = threadIdx.x;
  const int wave = tid >> 6;
  const int lane = tid & 63;
  const int quad = lane >> 4;
  const int l16  = lane & 15;
  const int n0   = wg * CWG;

  unsigned* gcnt = syncp;        // +1 per GEMM wg per step (128/step)
  unsigned* hcnt = syncp + 64;   // +1 per step wg per step (64/step)

  // ---- stage W tile into LDS in MFMA-fragment order (once) ----
  for (int i = 0; i < 32; ++i) {
    int idx = wave * 32 + i;
    int t2 = idx >> 6, kc = idx & 63;
    short8 v = *(const short8*)(wcat + (size_t)(n0 + t2 * 16 + l16) * KDIM
                                + kc * 32 + quad * 8);
    *(short8*)(smB + (size_t)idx * 512 + lane * 8) = v;
  }
  __syncthreads();

  const size_t rowoff = (size_t)(wave * 16 + l16) * HID + quad * 8;

  // ---- step-invariant state for step wgs: params + c in registers ----
  const int j = tid * 4;
  float cc[4];
  float wcf[4], wci[4], wco[4];
  float gf4[4], gi4[4], gg4[4], go4[4], gc4[4], bc4[4];
  float bf4[4], bi4[4], bg4[4], bo4[4];
  if (wg < BATCH) {
    LOAD4(cc,  c_ws + (size_t)wg * HID + j);
    LOAD4(wcf, w_ch + j);
    LOAD4(wci, w_ch + HID + j);
    LOAD4(wco, w_ch + 2 * HID + j);
    LOAD4(gf4, gamma_f + j); LOAD4(gi4, gamma_i + j);
    LOAD4(gg4, gamma_g + j); LOAD4(go4, gamma_o + j);
    LOAD4(gc4, gamma_c + j); LOAD4(bc4, beta_c + j);
    LOAD4(bf4, bias + j);           LOAD4(bi4, bias + HID + j);
    LOAD4(bg4, bias + 2 * HID + j); LOAD4(bo4, bias + 3 * HID + j);
  }
  const float invH = 1.0f / (float)HID;

  for (int t = 0; t < T_STEPS; ++t) {
    wait_ge(hcnt, 64u * (unsigned)t);

    // ---- A-fragment register prefetch (64 x 16B; static idx -> VGPRs) ----
    short8 aH[32], aX[32];
    if (POOL) {
      const unsigned short* ah = hA + (size_t)t * BATCH * HID + rowoff;
      const unsigned short* ax = xA + (size_t)t * BATCH * HID + rowoff;
#pragma unroll
      for (int kc = 0; kc < 32; ++kc) aH[kc] = *(const short8*)(ah + kc * 32);
#pragma unroll
      for (int kc = 0; kc < 32; ++kc) aX[kc] = *(const short8*)(ax + kc * 32);
    } else {
#pragma unroll
      for (int kc = 0; kc < 32; ++kc) aH[kc] = ld_a16_mall(hA + rowoff + kc * 32);
#pragma unroll
      for (int kc = 0; kc < 32; ++kc) aX[kc] = ld_a16_mall(xA + rowoff + kc * 32);
    }

    // ---- MFMA: 4 independent chains (2 col-tiles x even/odd kc) ----
    floatx4 z = {0.f, 0.f, 0.f, 0.f};
    floatx4 a00 = z, a01 = z, a10 = z, a11 = z;
#pragma unroll
    for (int kc = 0; kc < 32; kc += 2) {
      short8 b00 = *(const short8*)(smB + (size_t)(kc)      * 512 + lane * 8);
      short8 b10 = *(const short8*)(smB + (size_t)(64 + kc) * 512 + lane * 8);
      short8 b01 = *(const short8*)(smB + (size_t)(kc + 1)      * 512 + lane * 8);
      short8 b11 = *(const short8*)(smB + (size_t)(64 + kc + 1) * 512 + lane * 8);
      a00 = __builtin_amdgcn_mfma_f32_16x16x32_bf16(aH[kc],     b00, a00, 0, 0, 0);
      a10 = __builtin_amdgcn_mfma_f32_16x16x32_bf16(aH[kc],     b10, a10, 0, 0, 0);
      a01 = __builtin_amdgcn_mfma_f32_16x16x32_bf16(aH[kc + 1], b01, a01, 0, 0, 0);
      a11 = __builtin_amdgcn_mfma_f32_16x16x32_bf16(aH[kc + 1], b11, a11, 0, 0, 0);
    }
#pragma unroll
    for (int kc = 0; kc < 32; kc += 2) {
      short8 b00 = *(const short8*)(smB + (size_t)(32 + kc)      * 512 + lane * 8);
      short8 b10 = *(const short8*)(smB + (size_t)(96 + kc)      * 512 + lane * 8);
      short8 b01 = *(const short8*)(smB + (size_t)(32 + kc + 1)  * 512 + lane * 8);
      short8 b11 = *(const short8*)(smB + (size_t)(96 + kc + 1)  * 512 + lane * 8);
      a00 = __builtin_amdgcn_mfma_f32_16x16x32_bf16(aX[kc],     b00, a00, 0, 0, 0);
      a10 = __builtin_amdgcn_mfma_f32_16x16x32_bf16(aX[kc],     b10, a10, 0, 0, 0);
      a01 = __builtin_amdgcn_mfma_f32_16x16x32_bf16(aX[kc + 1], b01, a01, 0, 0, 0);
      a11 = __builtin_amdgcn_mfma_f32_16x16x32_bf16(aX[kc + 1], b11, a11, 0, 0, 0);
    }
    floatx4 acc0 = a00 + a01;
    floatx4 acc1 = a10 + a11;

    // C/D layout (m89-verified): col = l16 (in tile), row = quad*4 + r
#pragma unroll
    for (int r = 0; r < 4; ++r) {
      int m = wave * 16 + quad * 4 + r;
      float* gm = gates + (size_t)m * GDIM + n0 + l16;
      st_u32_mall(gm,      __float_as_uint(acc0[r]));
      st_u32_mall(gm + 16, __float_as_uint(acc1[r]));
    }
    arrive_(gcnt);

    if (wg < BATCH) {
      const int has_next = (t + 1 < T_STEPS);
      float4 xv;
      if (!POOL && has_next)       // issue before the spin: hides HBM latency
        xv = *(const float4*)(input + (size_t)(t + 1) * BATCH * HID
                              + (size_t)wg * HID + j);

      wait_ge(gcnt, 128u * (unsigned)(t + 1));

      float fh[4], ih[4], gh[4], oh[4];
      const float* grow = gates + (size_t)wg * GDIM;
      ld4f_mall(fh, grow + j);
      ld4f_mall(ih, grow + HID + j);
      ld4f_mall(gh, grow + 2 * HID + j);
      ld4f_mall(oh, grow + 3 * HID + j);

      if (!POOL && has_next)       // x_{t+1} conversion off the critical tail
        st4h_mall(xA + (size_t)wg * HID + j, xv.x, xv.y, xv.z, xv.w);

      float af[4], ai[4], ag[4];
      float s[6] = {0, 0, 0, 0, 0, 0};
#pragma unroll
      for (int r = 0; r < 4; ++r) {
        af[r] = fh[r] + wcf[r] * cc[r];
        ai[r] = ih[r] + wci[r] * cc[r];
        ag[r] = gh[r];
        s[0] += af[r]; s[1] += af[r] * af[r];
        s[2] += ai[r]; s[3] += ai[r] * ai[r];
        s[4] += ag[r]; s[5] += ag[r] * ag[r];
      }
      block_reduce<6>(s, sm, tid);
      float mu_f = s[0] * invH, is_f = rsqrtf(s[1] * invH - mu_f * mu_f + 1e-5f);
      float mu_i = s[2] * invH, is_i = rsqrtf(s[3] * invH - mu_i * mu_i + 1e-5f);
      float mu_g = s[4] * invH, is_g = rsqrtf(s[5] * invH - mu_g * mu_g + 1e-5f);

      float cn[4], ao[4];
      float s2[4] = {0, 0, 0, 0};
#pragma unroll
      for (int r = 0; r < 4; ++r) {
        float f = sigmoid_((af[r] - mu_f) * is_f * gf4[r] + bf4[r]);
        float i = sigmoid_((ai[r] - mu_i) * is_i * gi4[r] + bi4[r]);
        float g = tanh_((ag[r] - mu_g) * is_g * gg4[r] + bg4[r]);
        cn[r] = f * cc[r] + i * g;
        ao[r] = oh[r] + wco[r] * cn[r];
        s2[0] += cn[r]; s2[1] += cn[r] * cn[r];
        s2[2] += ao[r]; s2[3] += ao[r] * ao[r];
      }
#pragma unroll
      for (int r = 0; r < 4; ++r) cc[r] = cn[r];   // c stays in registers

      block_reduce<4>(s2, sm + 24, tid);
      float mu_c = s2[0] * invH, is_c = rsqrtf(s2[1] * invH - mu_c * mu_c + 1e-5f);
      float mu_o = s2[2] * invH, is_o = rsqrtf(s2[3] * invH - mu_o * mu_o + 1e-5f);

      float h4[4];
#pragma unroll
      for (int r = 0; r < 4; ++r) {
        float cl = (cn[r] - mu_c) * is_c * gc4[r] + bc4[r];
        float o  = sigmoid_((ao[r] - mu_o) * is_o * go4[r] + bo4[r]);
        h4[r] = o * tanh_(cl);
      }
      { float4 tt; tt.x = h4[0]; tt.y = h4[1]; tt.z = h4[2]; tt.w = h4[3];
        *(float4*)(out + (size_t)t * BATCH * HID + (size_t)wg * HID + j) = tt; }
      if (has_next) {
        unsigned short* hd = POOL
            ? hA + (size_t)(t + 1) * BATCH * HID + (size_t)wg * HID + j
            : hA + (size_t)wg * HID + j;
        st4h_mall(hd, h4[0], h4[1], h4[2], h4[3]);
      }
      arrive_(hcnt);
    }
  }

  if (wg < BATCH) {   // final cell state for the output copy
    float4 tt; tt.x = cc[0]; tt.y = cc[1]; tt.z = cc[2]; tt.w = cc[3];
    *(float4*)(c_ws + (size_t)wg * HID + j) = tt;
  }
}

// ---------------------------------------------------------------------------
extern "C" void kernel_launch(void* const* d_in, const int* in_sizes, int n_in,
                              void* d_out, int out_size, void* d_ws, size_t ws_size,
                              hipStream_t stream) {
  (void)in_sizes; (void)n_in; (void)out_size;
  const float* input   = (const float*)d_in[0];
  const float* hidden  = (const float*)d_in[1];
  const float* cell    = (const float*)d_in[2];
  const float* w_ih    = (const float*)d_in[3];
  const float* w_hh    = (const float*)d_in[4];
  const float* w_ch    = (const float*)d_in[5];
  const float* bias    = (const float*)d_in[6];
  const float* gamma_f = (const float*)d_in[7];
  const float* gamma_i = (const float*)d_in[8];
  const float* gamma_g = (const float*)d_in[9];
  const float* gamma_o = (const float*)d_in[10];
  const float* gamma_c = (const float*)d_in[11];
  const float* beta_c  = (const float*)d_in[12];
  float* out = (float*)d_out;

  const size_t SZ_WCAT = (size_t)GDIM * KDIM * sizeof(unsigned short); // 16 MB
  const size_t SZ_SEQ  = (size_t)T_STEPS * BATCH * HID * sizeof(unsigned short); // 64 MB
  const size_t SZ_GATE = (size_t)BATCH * GDIM * sizeof(float);         // 1 MB
  const size_t SZ_VEC  = (size_t)BATCH * HID * sizeof(float);          // 256 KB
  const size_t NEED_POOL = SZ_WCAT + 2 * SZ_SEQ + SZ_GATE + SZ_VEC + 4096;

  char* p = (char*)d_ws;
  unsigned short* wcat = (unsigned short*)p;            p += SZ_WCAT;
  const int pool = (ws_size >= NEED_POOL) ? 1 : 0;

  unsigned short *hA, *xA;
  if (pool) {
    xA = (unsigned short*)p; p += SZ_SEQ;               // xall: bf16 x, all t
    hA = (unsigned short*)p; p += SZ_SEQ;               // h pool: 512 slots
  } else {
    hA = (unsigned short*)p; p += (size_t)BATCH * HID * 2;
    xA = (unsigned short*)p; p += (size_t)BATCH * HID * 2;
  }
  float* gates = (float*)p;  p += SZ_GATE;
  float* c_ws  = (float*)p;  p += SZ_VEC;
  unsigned* syncp = (unsigned*)p;

  cvt_w_kernel<<<(GDIM * KDIM / 4) / 256, 256, 0, stream>>>(w_hh, w_ih, wcat);
  if (pool)
    cvt_x_kernel<<<(T_STEPS * BATCH * HID / 8) / 256, 256, 0, stream>>>(input, xA);
  init_kernel<<<BATCH, 256, 0, stream>>>(hidden, input, cell, hA, xA, c_ws);
  hipMemsetAsync(syncp, 0, 512, stream);   // counters zero on every replay

  if (pool)
    lstm_persist<1><<<NWG, 256, 0, stream>>>(
        wcat, input, gates, c_ws, w_ch, bias, gamma_f, gamma_i, gamma_g,
        gamma_o, gamma_c, beta_c, out, hA, xA, syncp);
  else
    lstm_persist<0><<<NWG, 256, 0, stream>>>(
        wcat, input, gates, c_ws, w_ch, bias, gamma_f, gamma_i, gamma_g,
        gamma_o, gamma_c, beta_c, out, hA, xA, syncp);

  const size_t OUT0 = (size_t)T_STEPS * BATCH * HID;
  hipMemcpyAsync(out + OUT0, out + (OUT0 - BATCH * HID),
                 (size_t)BATCH * HID * sizeof(float), hipMemcpyDeviceToDevice, stream);
  hipMemcpyAsync(out + OUT0 + BATCH * HID, c_ws,
                 (size_t)BATCH * HID * sizeof(float), hipMemcpyDeviceToDevice, stream);
}

// Round 3
// 7244.805 us; speedup vs baseline: 2.0301x; 1.4492x over previous
//
#include <hip/hip_runtime.h>

#define T_STEPS 512
#define BATCH   64
#define HID     1024
#define GDIM    4096   // 4*H gate columns
#define KDIM    2048   // [h | x] fused K
#define NGW     128    // GEMM wgs (32 cols each)
#define NSW     64     // step/LN wgs (1 batch row each)
#define CWG     32     // gate columns per GEMM wg
#define BHID    (BATCH * HID)

using short8  = __attribute__((ext_vector_type(8))) short;
using floatx4 = __attribute__((ext_vector_type(4))) float;
typedef unsigned long long u64;

__device__ inline unsigned short bf16_rne(float f) {
  union { float f; unsigned u; } x; x.f = f;
  unsigned r = x.u + 0x7FFFu + ((x.u >> 16) & 1u);
  return (unsigned short)(r >> 16);
}

__device__ inline float sigmoid_(float x) { return 1.0f / (1.0f + __expf(-x)); }
__device__ inline float tanh_(float x) {
  float e = __expf(-2.0f * fabsf(x));
  float r = (1.0f - e) / (1.0f + e);
  return copysignf(r, x);
}

#define LOAD4(dst, ptr) { float4 _t4 = *(const float4*)(ptr); \
  dst[0]=_t4.x; dst[1]=_t4.y; dst[2]=_t4.z; dst[3]=_t4.w; }

// ---------------------------------------------------------------------------
// MALL-coherent primitives (relaxed agent-scope atomics -> cache-bypass,
// no fences, fully pipelined). Proven correct+faster in round 2.
// ---------------------------------------------------------------------------
__device__ inline u64 ld_u64_mall(const void* p) {
  return __hip_atomic_load((const u64*)p, __ATOMIC_RELAXED, __HIP_MEMORY_SCOPE_AGENT);
}
__device__ inline void st_u64_mall(void* p, u64 v) {
  __hip_atomic_store((u64*)p, v, __ATOMIC_RELAXED, __HIP_MEMORY_SCOPE_AGENT);
}
__device__ inline void st_u32_mall(void* p, unsigned v) {
  __hip_atomic_store((unsigned*)p, v, __ATOMIC_RELAXED, __HIP_MEMORY_SCOPE_AGENT);
}
__device__ inline unsigned ld_u32_mall(const void* p) {
  return __hip_atomic_load((const unsigned*)p, __ATOMIC_RELAXED, __HIP_MEMORY_SCOPE_AGENT);
}
__device__ inline short8 ld_a16_mall(const unsigned short* p) {
  union { u64 q[2]; short8 v; } u;
  u.q[0] = ld_u64_mall(p);
  u.q[1] = ld_u64_mall(p + 4);
  return u.v;
}
__device__ inline void ld4f_mall(float* d, const float* p) {
  union { u64 q; float f[2]; } a, b;
  a.q = ld_u64_mall(p);
  b.q = ld_u64_mall(p + 2);
  d[0] = a.f[0]; d[1] = a.f[1]; d[2] = b.f[0]; d[3] = b.f[1];
}
__device__ inline void st4h_mall(unsigned short* p, float a, float b, float c, float d) {
  union { u64 q; unsigned short s[4]; } u;
  u.s[0] = bf16_rne(a); u.s[1] = bf16_rne(b); u.s[2] = bf16_rne(c); u.s[3] = bf16_rne(d);
  st_u64_mall(p, u.q);
}

// ---------------------------------------------------------------------------
// One-time: pack [W_hh | W_ih] into bf16 Wcat[4096][2048]
// ---------------------------------------------------------------------------
__global__ __launch_bounds__(256) void cvt_w_kernel(
    const float* __restrict__ w_hh, const float* __restrict__ w_ih,
    unsigned short* __restrict__ wcat)
{
  int idx  = blockIdx.x * 256 + threadIdx.x;
  int base = idx * 4;
  int g = base >> 11;
  int k = base & 2047;
  const float* src = (k < 1024) ? (w_hh + (size_t)g * 1024 + k)
                                : (w_ih + (size_t)g * 1024 + (k - 1024));
  float a = src[0], b = src[1], c = src[2], d = src[3];
  uint2 v;
  v.x = (unsigned)bf16_rne(a) | ((unsigned)bf16_rne(b) << 16);
  v.y = (unsigned)bf16_rne(c) | ((unsigned)bf16_rne(d) << 16);
  *(uint2*)(wcat + base) = v;
}

// ---------------------------------------------------------------------------
// One-time (xall mode): whole input stream -> bf16, read-only afterwards
// ---------------------------------------------------------------------------
__global__ __launch_bounds__(256) void cvt_x_kernel(
    const float* __restrict__ x, unsigned short* __restrict__ xall)
{
  size_t i = ((size_t)blockIdx.x * 256 + threadIdx.x) * 8;
  float4 a = *(const float4*)(x + i);
  float4 b = *(const float4*)(x + i + 4);
  union { unsigned short s[8]; uint4 v; } u;
  u.s[0] = bf16_rne(a.x); u.s[1] = bf16_rne(a.y); u.s[2] = bf16_rne(a.z); u.s[3] = bf16_rne(a.w);
  u.s[4] = bf16_rne(b.x); u.s[5] = bf16_rne(b.y); u.s[6] = bf16_rne(b.z); u.s[7] = bf16_rne(b.w);
  *(uint4*)(xall + i) = u.v;
}

// ---------------------------------------------------------------------------
// One-time: h0 -> bf16, x0 -> bf16, cell -> c_ws
// ---------------------------------------------------------------------------
__global__ __launch_bounds__(256) void init_kernel(
    const float* __restrict__ hidden, const float* __restrict__ x0,
    const float* __restrict__ cell,
    unsigned short* __restrict__ hdst, unsigned short* __restrict__ xdst,
    float* __restrict__ c_ws)
{
  const int b = blockIdx.x;
  const int j = threadIdx.x * 4;
  const size_t off = (size_t)b * HID + j;
  float4 h = *(const float4*)(hidden + off);
  float4 x = *(const float4*)(x0 + off);
  float4 c = *(const float4*)(cell + off);
  ushort4 hv, xv;
  hv.x = bf16_rne(h.x); hv.y = bf16_rne(h.y); hv.z = bf16_rne(h.z); hv.w = bf16_rne(h.w);
  xv.x = bf16_rne(x.x); xv.y = bf16_rne(x.y); xv.z = bf16_rne(x.z); xv.w = bf16_rne(x.w);
  *(ushort4*)(hdst + off) = hv;
  *(ushort4*)(xdst + off) = xv;
  *(float4*)(c_ws + off) = c;
}

// ---------------------------------------------------------------------------
template<int N>
__device__ inline void block_reduce(float* v, float* red, int tid) {
#pragma unroll
  for (int i = 0; i < N; ++i) {
    float x = v[i];
#pragma unroll
    for (int off = 32; off > 0; off >>= 1)
      x += __shfl_xor(x, off, 64);
    v[i] = x;
  }
  const int wave = tid >> 6;
  if ((tid & 63) == 0) {
#pragma unroll
    for (int i = 0; i < N; ++i) red[wave * N + i] = v[i];
  }
  __syncthreads();
#pragma unroll
  for (int i = 0; i < N; ++i)
    v[i] = red[i] + red[N + i] + red[2 * N + i] + red[3 * N + i];
}

#define MFMA16(a, b, c) __builtin_amdgcn_mfma_f32_16x16x32_bf16(a, b, c, 0, 0, 0)

// ---------------------------------------------------------------------------
// Persistent kernel, 192 wgs (all co-resident: 131 KiB LDS -> 1 wg/CU).
//   wgs 0..127  : GEMM. Own 32 gate cols (W tile in LDS). Per step: x-part
//                 MFMAs first (no h dependency), then per-lane spin on the
//                 64 h-flags, then h-part, bypass-store gates, store gflag.
//   wgs 128..191: LN/step for one batch row. Per-lane spin on 128 g-flags,
//                 bypass-load gate row, LN+pointwise, bypass-store h + flag.
// Flags: monotonic tags, one 64B-spaced word per producer wg, plain bypass
// stores (NO atomic RMW anywhere) -> zero serialization; waiters use one
// lane per flag, wave reconvergence = "all arrived".
// ---------------------------------------------------------------------------
template<int XALL>
__global__ __launch_bounds__(256, 1) void lstm_persist(
    const unsigned short* __restrict__ wcat,
    const float* __restrict__ input,
    const unsigned short* __restrict__ xA,   // XALL: xall; else single xbuf
    unsigned short* __restrict__ xbuf,       // fallback single x buffer
    float* __restrict__ gates, float* __restrict__ c_ws,
    const float* __restrict__ w_ch, const float* __restrict__ bias,
    const float* __restrict__ gamma_f, const float* __restrict__ gamma_i,
    const float* __restrict__ gamma_g, const float* __restrict__ gamma_o,
    const float* __restrict__ gamma_c, const float* __restrict__ beta_c,
    float* __restrict__ out,
    unsigned short* __restrict__ hbuf,
    unsigned* __restrict__ syncp)
{
  __shared__ __align__(16) unsigned short smB[CWG * KDIM];  // 128 KiB W tile
  __shared__ float sm[40];

  const int wg   = blockIdx.x;
  const int tid  = threadIdx.x;
  const int wave = tid >> 6;
  const int lane = tid & 63;
  const int quad = lane >> 4;
  const int l16  = lane & 15;

  unsigned* gflags = syncp;              // NGW flags, stride 16 u32 (64 B)
  unsigned* hflags = syncp + NGW * 16;   // NSW flags, stride 16 u32

  const floatx4 z = {0.f, 0.f, 0.f, 0.f};

  if (wg < NGW) {
    // =========================== GEMM wg =================================
    const int n0 = wg * CWG;
    // stage W tile into LDS in MFMA-fragment order (once)
    for (int i = 0; i < 32; ++i) {
      int idx = wave * 32 + i;
      int t2 = idx >> 6, kc = idx & 63;
      short8 v = *(const short8*)(wcat + (size_t)(n0 + t2 * 16 + l16) * KDIM
                                  + kc * 32 + quad * 8);
      *(short8*)(smB + (size_t)idx * 512 + lane * 8) = v;
    }
    __syncthreads();

    const size_t rowoff = (size_t)(wave * 16 + l16) * HID + quad * 8;

    for (int t = 0; t < T_STEPS; ++t) {
      // ---- x-part: depends only on the input; off the critical path ----
      floatx4 x0e = z, x1e = z, x0o = z, x1o = z;
      if (XALL) {
        const unsigned short* ax = xA + (size_t)t * BHID + rowoff;
#pragma unroll
        for (int kc = 0; kc < 32; kc += 2) {
          short8 ae  = *(const short8*)(ax + kc * 32);
          short8 ao  = *(const short8*)(ax + (kc + 1) * 32);
          short8 b0e = *(const short8*)(smB + (size_t)(32 + kc) * 512 + lane * 8);
          short8 b1e = *(const short8*)(smB + (size_t)(96 + kc) * 512 + lane * 8);
          short8 b0o = *(const short8*)(smB + (size_t)(33 + kc) * 512 + lane * 8);
          short8 b1o = *(const short8*)(smB + (size_t)(97 + kc) * 512 + lane * 8);
          x0e = MFMA16(ae, b0e, x0e); x1e = MFMA16(ae, b1e, x1e);
          x0o = MFMA16(ao, b0o, x0o); x1o = MFMA16(ao, b1o, x1o);
        }
      }

      // ---- wait for h_t: one lane per h-flag, parallel spin ----
      if (tid < NSW) {
        const unsigned* fp = hflags + tid * 16;
        while (ld_u32_mall(fp) < (unsigned)t) { }
      }
      __syncthreads();

      if (!XALL) {   // fallback: x_t staged by step wgs last step (bypass)
#pragma unroll
        for (int kc = 0; kc < 32; kc += 2) {
          short8 ae  = ld_a16_mall(xA + rowoff + kc * 32);
          short8 ao  = ld_a16_mall(xA + rowoff + (kc + 1) * 32);
          short8 b0e = *(const short8*)(smB + (size_t)(32 + kc) * 512 + lane * 8);
          short8 b1e = *(const short8*)(smB + (size_t)(96 + kc) * 512 + lane * 8);
          short8 b0o = *(const short8*)(smB + (size_t)(33 + kc) * 512 + lane * 8);
          short8 b1o = *(const short8*)(smB + (size_t)(97 + kc) * 512 + lane * 8);
          x0e = MFMA16(ae, b0e, x0e); x1e = MFMA16(ae, b1e, x1e);
          x0o = MFMA16(ao, b0o, x0o); x1o = MFMA16(ao, b1o, x1o);
        }
      }

      // ---- h-part: prefetch all A-fragments, then MFMA ----
      short8 aH[32];
#pragma unroll
      for (int kc = 0; kc < 32; ++kc)
        aH[kc] = ld_a16_mall(hbuf + rowoff + kc * 32);

      floatx4 h0e = z, h1e = z, h0o = z, h1o = z;
#pragma unroll
      for (int kc = 0; kc < 32; kc += 2) {
        short8 b0e = *(const short8*)(smB + (size_t)kc * 512 + lane * 8);
        short8 b1e = *(const short8*)(smB + (size_t)(64 + kc) * 512 + lane * 8);
        short8 b0o = *(const short8*)(smB + (size_t)(kc + 1) * 512 + lane * 8);
        short8 b1o = *(const short8*)(smB + (size_t)(65 + kc) * 512 + lane * 8);
        h0e = MFMA16(aH[kc],     b0e, h0e); h1e = MFMA16(aH[kc],     b1e, h1e);
        h0o = MFMA16(aH[kc + 1], b0o, h0o); h1o = MFMA16(aH[kc + 1], b1o, h1o);
      }

      // C/D layout (m89-verified): col = l16 (in tile), row = quad*4 + r
#pragma unroll
      for (int r = 0; r < 4; ++r) {
        int m = wave * 16 + quad * 4 + r;
        float* gm = gates + (size_t)m * GDIM + n0 + l16;
        st_u32_mall(gm,      __float_as_uint((h0e[r] + h0o[r]) + (x0e[r] + x0o[r])));
        st_u32_mall(gm + 16, __float_as_uint((h1e[r] + h1o[r]) + (x1e[r] + x1o[r])));
      }
      asm volatile("s_waitcnt vmcnt(0)" ::: "memory");  // gates at MALL
      __syncthreads();
      if (tid == 0)
        st_u32_mall(gflags + wg * 16, (unsigned)(t + 1));
    }
  } else {
    // =========================== step/LN wg ==============================
    const int b = wg - NGW;
    const int j = tid * 4;

    float cc[4], wcf[4], wci[4], wco[4];
    float gf4[4], gi4[4], gg4[4], go4[4], gc4[4], bc4[4];
    float bf4[4], bi4[4], bg4[4], bo4[4];
    LOAD4(cc,  c_ws + (size_t)b * HID + j);
    LOAD4(wcf, w_ch + j);
    LOAD4(wci, w_ch + HID + j);
    LOAD4(wco, w_ch + 2 * HID + j);
    LOAD4(gf4, gamma_f + j); LOAD4(gi4, gamma_i + j);
    LOAD4(gg4, gamma_g + j); LOAD4(go4, gamma_o + j);
    LOAD4(gc4, gamma_c + j); LOAD4(bc4, beta_c + j);
    LOAD4(bf4, bias + j);           LOAD4(bi4, bias + HID + j);
    LOAD4(bg4, bias + 2 * HID + j); LOAD4(bo4, bias + 3 * HID + j);
    const float invH = 1.0f / (float)HID;

    for (int t = 0; t < T_STEPS; ++t) {
      const int has_next = (t + 1 < T_STEPS);
      float4 xv;
      if (!XALL && has_next)    // early issue: HBM latency hides under spin
        xv = *(const float4*)(input + (size_t)(t + 1) * BHID + (size_t)b * HID + j);

      // ---- wait for all 128 gate tiles: one lane per g-flag ----
      if (tid < NGW) {
        const unsigned* fp = gflags + tid * 16;
        while (ld_u32_mall(fp) < (unsigned)(t + 1)) { }
      }
      __syncthreads();

      float fh[4], ih[4], gh[4], oh[4];
      const float* grow = gates + (size_t)b * GDIM;
      ld4f_mall(fh, grow + j);
      ld4f_mall(ih, grow + HID + j);
      ld4f_mall(gh, grow + 2 * HID + j);
      ld4f_mall(oh, grow + 3 * HID + j);

      if (!XALL && has_next)    // publish x_{t+1} before the h flag
        st4h_mall(xbuf + (size_t)b * HID + j, xv.x, xv.y, xv.z, xv.w);

      float af[4], ai[4], ag[4];
      float s[6] = {0, 0, 0, 0, 0, 0};
#pragma unroll
      for (int r = 0; r < 4; ++r) {
        af[r] = fh[r] + wcf[r] * cc[r];
        ai[r] = ih[r] + wci[r] * cc[r];
        ag[r] = gh[r];
        s[0] += af[r]; s[1] += af[r] * af[r];
        s[2] += ai[r]; s[3] += ai[r] * ai[r];
        s[4] += ag[r]; s[5] += ag[r] * ag[r];
      }
      block_reduce<6>(s, sm, tid);
      float mu_f = s[0] * invH, is_f = rsqrtf(s[1] * invH - mu_f * mu_f + 1e-5f);
      float mu_i = s[2] * invH, is_i = rsqrtf(s[3] * invH - mu_i * mu_i + 1e-5f);
      float mu_g = s[4] * invH, is_g = rsqrtf(s[5] * invH - mu_g * mu_g + 1e-5f);

      float cn[4], ao[4];
      float s2[4] = {0, 0, 0, 0};
#pragma unroll
      for (int r = 0; r < 4; ++r) {
        float f = sigmoid_((af[r] - mu_f) * is_f * gf4[r] + bf4[r]);
        float i = sigmoid_((ai[r] - mu_i) * is_i * gi4[r] + bi4[r]);
        float g = tanh_((ag[r] - mu_g) * is_g * gg4[r] + bg4[r]);
        cn[r] = f * cc[r] + i * g;
        ao[r] = oh[r] + wco[r] * cn[r];
        s2[0] += cn[r]; s2[1] += cn[r] * cn[r];
        s2[2] += ao[r]; s2[3] += ao[r] * ao[r];
      }
#pragma unroll
      for (int r = 0; r < 4; ++r) cc[r] = cn[r];   // c lives in registers

      block_reduce<4>(s2, sm + 24, tid);
      float mu_c = s2[0] * invH, is_c = rsqrtf(s2[1] * invH - mu_c * mu_c + 1e-5f);
      float mu_o = s2[2] * invH, is_o = rsqrtf(s2[3] * invH - mu_o * mu_o + 1e-5f);

      float h4[4];
#pragma unroll
      for (int r = 0; r < 4; ++r) {
        float cl = (cn[r] - mu_c) * is_c * gc4[r] + bc4[r];
        float o  = sigmoid_((ao[r] - mu_o) * is_o * go4[r] + bo4[r]);
        h4[r] = o * tanh_(cl);
      }
      { float4 tt; tt.x = h4[0]; tt.y = h4[1]; tt.z = h4[2]; tt.w = h4[3];
        *(float4*)(out + (size_t)t * BHID + (size_t)b * HID + j) = tt; }
      st4h_mall(hbuf + (size_t)b * HID + j, h4[0], h4[1], h4[2], h4[3]);

      asm volatile("s_waitcnt vmcnt(0)" ::: "memory");  // h (and x) at MALL
      __syncthreads();
      if (tid == 0)
        st_u32_mall(hflags + b * 16, (unsigned)(t + 1));
    }

    { float4 tt; tt.x = cc[0]; tt.y = cc[1]; tt.z = cc[2]; tt.w = cc[3];
      *(float4*)(c_ws + (size_t)b * HID + j) = tt; }
  }
}

// ---------------------------------------------------------------------------
extern "C" void kernel_launch(void* const* d_in, const int* in_sizes, int n_in,
                              void* d_out, int out_size, void* d_ws, size_t ws_size,
                              hipStream_t stream) {
  (void)in_sizes; (void)n_in; (void)out_size;
  const float* input   = (const float*)d_in[0];
  const float* hidden  = (const float*)d_in[1];
  const float* cell    = (const float*)d_in[2];
  const float* w_ih    = (const float*)d_in[3];
  const float* w_hh    = (const float*)d_in[4];
  const float* w_ch    = (const float*)d_in[5];
  const float* bias    = (const float*)d_in[6];
  const float* gamma_f = (const float*)d_in[7];
  const float* gamma_i = (const float*)d_in[8];
  const float* gamma_g = (const float*)d_in[9];
  const float* gamma_o = (const float*)d_in[10];
  const float* gamma_c = (const float*)d_in[11];
  const float* beta_c  = (const float*)d_in[12];
  float* out = (float*)d_out;

  const size_t SZ_WCAT = (size_t)GDIM * KDIM * sizeof(unsigned short);   // 16 MB
  const size_t SZ_XALL = (size_t)T_STEPS * BHID * sizeof(unsigned short); // 64 MB
  const size_t SZ_BUF  = (size_t)BHID * sizeof(unsigned short);          // 128 KB
  const size_t SZ_GATE = (size_t)BATCH * GDIM * sizeof(float);           // 1 MB
  const size_t SZ_VEC  = (size_t)BHID * sizeof(float);                   // 256 KB
  const size_t SZ_FLAG = 16384;
  const size_t NEED_XALL = SZ_WCAT + SZ_XALL + SZ_BUF + SZ_GATE + SZ_VEC + SZ_FLAG;

  char* p = (char*)d_ws;
  unsigned short* wcat = (unsigned short*)p;  p += SZ_WCAT;
  const int xall = (ws_size >= NEED_XALL) ? 1 : 0;

  unsigned short *xA, *xbuf;
  if (xall) { xA = (unsigned short*)p; p += SZ_XALL; xbuf = xA; }
  else      { xA = (unsigned short*)p; p += SZ_BUF;  xbuf = xA; }
  unsigned short* hbuf = (unsigned short*)p;  p += SZ_BUF;
  float* gates = (float*)p;  p += SZ_GATE;
  float* c_ws  = (float*)p;  p += SZ_VEC;
  unsigned* syncp = (unsigned*)p;

  cvt_w_kernel<<<(GDIM * KDIM / 4) / 256, 256, 0, stream>>>(w_hh, w_ih, wcat);
  if (xall)
    cvt_x_kernel<<<((size_t)T_STEPS * BHID / 8) / 256, 256, 0, stream>>>(input, xA);
  init_kernel<<<BATCH, 256, 0, stream>>>(hidden, input, cell, hbuf, xA, c_ws);
  hipMemsetAsync(syncp, 0, SZ_FLAG, stream);   // flags zero on every replay

  if (xall)
    lstm_persist<1><<<NGW + NSW, 256, 0, stream>>>(
        wcat, input, xA, xbuf, gates, c_ws, w_ch, bias, gamma_f, gamma_i,
        gamma_g, gamma_o, gamma_c, beta_c, out, hbuf, syncp);
  else
    lstm_persist<0><<<NGW + NSW, 256, 0, stream>>>(
        wcat, input, xA, xbuf, gates, c_ws, w_ch, bias, gamma_f, gamma_i,
        gamma_g, gamma_o, gamma_c, beta_c, out, hbuf, syncp);

  const size_t OUT0 = (size_t)T_STEPS * BHID;
  hipMemcpyAsync(out + OUT0, out + (OUT0 - BHID),
                 (size_t)BHID * sizeof(float), hipMemcpyDeviceToDevice, stream);
  hipMemcpyAsync(out + OUT0 + BHID, c_ws,
                 (size_t)BHID * sizeof(float), hipMemcpyDeviceToDevice, stream);
}

// Round 4
// 7010.372 us; speedup vs baseline: 2.0980x; 1.0334x over previous
//
#include <hip/hip_runtime.h>

#define T_STEPS 512
#define BATCH   64
#define HID     1024
#define GDIM    4096   // 4*H gate columns
#define KDIM    2048   // [h | x] fused K
#define NGW     128    // GEMM wgs (32 cols each)
#define NSW     64     // step/LN wgs (1 batch row each)
#define CWG     32     // gate columns per GEMM wg
#define BHID    (BATCH * HID)

using short8  = __attribute__((ext_vector_type(8))) short;
using floatx4 = __attribute__((ext_vector_type(4))) float;
typedef unsigned long long u64;

__device__ inline unsigned short bf16_rne(float f) {
  union { float f; unsigned u; } x; x.f = f;
  unsigned r = x.u + 0x7FFFu + ((x.u >> 16) & 1u);
  return (unsigned short)(r >> 16);
}

__device__ inline float sigmoid_(float x) { return 1.0f / (1.0f + __expf(-x)); }
__device__ inline float tanh_(float x) {
  float e = __expf(-2.0f * fabsf(x));
  float r = (1.0f - e) / (1.0f + e);
  return copysignf(r, x);
}

#define LOAD4(dst, ptr) { float4 _t4 = *(const float4*)(ptr); \
  dst[0]=_t4.x; dst[1]=_t4.y; dst[2]=_t4.z; dst[3]=_t4.w; }

// ---------------------------------------------------------------------------
// MALL-coherent primitives (relaxed agent-scope atomics -> cache-bypass,
// no fences, fully pipelined).
// ---------------------------------------------------------------------------
__device__ inline u64 ld_u64_mall(const void* p) {
  return __hip_atomic_load((const u64*)p, __ATOMIC_RELAXED, __HIP_MEMORY_SCOPE_AGENT);
}
__device__ inline void st_u64_mall(void* p, u64 v) {
  __hip_atomic_store((u64*)p, v, __ATOMIC_RELAXED, __HIP_MEMORY_SCOPE_AGENT);
}
__device__ inline void st_u32_mall(void* p, unsigned v) {
  __hip_atomic_store((unsigned*)p, v, __ATOMIC_RELAXED, __HIP_MEMORY_SCOPE_AGENT);
}
__device__ inline unsigned ld_u32_mall(const void* p) {
  return __hip_atomic_load((const unsigned*)p, __ATOMIC_RELAXED, __HIP_MEMORY_SCOPE_AGENT);
}
__device__ inline short8 ld_a16_mall(const unsigned short* p) {
  union { u64 q[2]; short8 v; } u;
  u.q[0] = ld_u64_mall(p);
  u.q[1] = ld_u64_mall(p + 4);
  return u.v;
}
__device__ inline void ld4f_mall(float* d, const float* p) {
  union { u64 q; float f[2]; } a, b;
  a.q = ld_u64_mall(p);
  b.q = ld_u64_mall(p + 2);
  d[0] = a.f[0]; d[1] = a.f[1]; d[2] = b.f[0]; d[3] = b.f[1];
}
__device__ inline void st4h_mall(unsigned short* p, float a, float b, float c, float d) {
  union { u64 q; unsigned short s[4]; } u;
  u.s[0] = bf16_rne(a); u.s[1] = bf16_rne(b); u.s[2] = bf16_rne(c); u.s[3] = bf16_rne(d);
  st_u64_mall(p, u.q);
}

// ---------------------------------------------------------------------------
// One-time: pack [W_hh | W_ih] into bf16 Wcat[4096][2048]
// ---------------------------------------------------------------------------
__global__ __launch_bounds__(256) void cvt_w_kernel(
    const float* __restrict__ w_hh, const float* __restrict__ w_ih,
    unsigned short* __restrict__ wcat)
{
  int idx  = blockIdx.x * 256 + threadIdx.x;
  int base = idx * 4;
  int g = base >> 11;
  int k = base & 2047;
  const float* src = (k < 1024) ? (w_hh + (size_t)g * 1024 + k)
                                : (w_ih + (size_t)g * 1024 + (k - 1024));
  float a = src[0], b = src[1], c = src[2], d = src[3];
  uint2 v;
  v.x = (unsigned)bf16_rne(a) | ((unsigned)bf16_rne(b) << 16);
  v.y = (unsigned)bf16_rne(c) | ((unsigned)bf16_rne(d) << 16);
  *(uint2*)(wcat + base) = v;
}

// ---------------------------------------------------------------------------
// One-time (xall modes): whole input stream -> bf16, read-only afterwards
// ---------------------------------------------------------------------------
__global__ __launch_bounds__(256) void cvt_x_kernel(
    const float* __restrict__ x, unsigned short* __restrict__ xall)
{
  size_t i = ((size_t)blockIdx.x * 256 + threadIdx.x) * 8;
  float4 a = *(const float4*)(x + i);
  float4 b = *(const float4*)(x + i + 4);
  union { unsigned short s[8]; uint4 v; } u;
  u.s[0] = bf16_rne(a.x); u.s[1] = bf16_rne(a.y); u.s[2] = bf16_rne(a.z); u.s[3] = bf16_rne(a.w);
  u.s[4] = bf16_rne(b.x); u.s[5] = bf16_rne(b.y); u.s[6] = bf16_rne(b.z); u.s[7] = bf16_rne(b.w);
  *(uint4*)(xall + i) = u.v;
}

// ---------------------------------------------------------------------------
// One-time: h0 -> bf16 (pool slot 0 / single buffer), x0 -> bf16, cell -> c_ws
// ---------------------------------------------------------------------------
__global__ __launch_bounds__(256) void init_kernel(
    const float* __restrict__ hidden, const float* __restrict__ x0,
    const float* __restrict__ cell,
    unsigned short* __restrict__ hdst, unsigned short* __restrict__ xdst,
    float* __restrict__ c_ws)
{
  const int b = blockIdx.x;
  const int j = threadIdx.x * 4;
  const size_t off = (size_t)b * HID + j;
  float4 h = *(const float4*)(hidden + off);
  float4 x = *(const float4*)(x0 + off);
  float4 c = *(const float4*)(cell + off);
  ushort4 hv, xv;
  hv.x = bf16_rne(h.x); hv.y = bf16_rne(h.y); hv.z = bf16_rne(h.z); hv.w = bf16_rne(h.w);
  xv.x = bf16_rne(x.x); xv.y = bf16_rne(x.y); xv.z = bf16_rne(x.z); xv.w = bf16_rne(x.w);
  *(ushort4*)(hdst + off) = hv;
  *(ushort4*)(xdst + off) = xv;
  *(float4*)(c_ws + off) = c;
}

// ---------------------------------------------------------------------------
template<int N>
__device__ inline void block_reduce(float* v, float* red, int tid) {
#pragma unroll
  for (int i = 0; i < N; ++i) {
    float x = v[i];
#pragma unroll
    for (int off = 32; off > 0; off >>= 1)
      x += __shfl_xor(x, off, 64);
    v[i] = x;
  }
  const int wave = tid >> 6;
  if ((tid & 63) == 0) {
#pragma unroll
    for (int i = 0; i < N; ++i) red[wave * N + i] = v[i];
  }
  __syncthreads();
#pragma unroll
  for (int i = 0; i < N; ++i)
    v[i] = red[i] + red[N + i] + red[2 * N + i] + red[3 * N + i];
}

#define MFMA16(a, b, c) __builtin_amdgcn_mfma_f32_16x16x32_bf16(a, b, c, 0, 0, 0)

// ---------------------------------------------------------------------------
// Persistent kernel, 192 wgs (1/CU via 128 KiB LDS -> all co-resident).
// MODE 2: xall + h-pool (fresh slot per step; producers bypass-store so data
//         lands at MALL; consumers CACHED-read -> XCD L2 shares the broadcast,
//         16x less MALL traffic. Fresh addresses can't be stale: dispatch
//         acquire invalidates L2 and addresses never repeat in-dispatch.)
// MODE 1: xall + single bypass h buffer (round-3 behavior)
// MODE 0: minimal ws: per-step x staging via step wgs + bypass h
// Flags: monotonic tags, packed at 4 B stride (poll = few lines), plain
// bypass stores, one lane per flag on the waiter side.
// ---------------------------------------------------------------------------
template<int MODE>
__global__ __launch_bounds__(256, 1) void lstm_persist(
    const unsigned short* __restrict__ wcat,
    const float* __restrict__ input,
    const unsigned short* __restrict__ xA,   // MODE>=1: xall; else xbuf
    unsigned short* __restrict__ xbuf,       // MODE 0 single x buffer
    float* __restrict__ gates, float* __restrict__ c_ws,
    const float* __restrict__ w_ch, const float* __restrict__ bias,
    const float* __restrict__ gamma_f, const float* __restrict__ gamma_i,
    const float* __restrict__ gamma_g, const float* __restrict__ gamma_o,
    const float* __restrict__ gamma_c, const float* __restrict__ beta_c,
    float* __restrict__ out,
    unsigned short* __restrict__ hA,         // MODE 2: pool; else single buf
    unsigned* __restrict__ syncp)
{
  __shared__ __align__(16) unsigned short smB[CWG * KDIM];  // 128 KiB W tile
  __shared__ float sm[40];

  const int wg   = blockIdx.x;
  const int tid  = threadIdx.x;
  const int wave = tid >> 6;
  const int lane = tid & 63;
  const int quad = lane >> 4;
  const int l16  = lane & 15;

  unsigned* gflags = syncp;          // NGW flags, 4B stride (8 lines)
  unsigned* hflags = syncp + 512;    // NSW flags, 4B stride (4 lines)

  const floatx4 z = {0.f, 0.f, 0.f, 0.f};

  if (wg < NGW) {
    // =========================== GEMM wg =================================
    const int n0 = wg * CWG;
    for (int i = 0; i < 32; ++i) {   // stage W tile (MFMA-fragment order)
      int idx = wave * 32 + i;
      int t2 = idx >> 6, kc = idx & 63;
      short8 v = *(const short8*)(wcat + (size_t)(n0 + t2 * 16 + l16) * KDIM
                                  + kc * 32 + quad * 8);
      *(short8*)(smB + (size_t)idx * 512 + lane * 8) = v;
    }
    __syncthreads();

    const size_t rowoff = (size_t)(wave * 16 + l16) * HID + quad * 8;

    for (int t = 0; t < T_STEPS; ++t) {
      // ---- x-part: input-only dependency; runs during the LN window ----
      floatx4 x0e = z, x1e = z, x0o = z, x1o = z;
      if (MODE >= 1) {
        const unsigned short* ax = xA + (size_t)t * BHID + rowoff;
#pragma unroll
        for (int kc = 0; kc < 32; kc += 2) {
          short8 ae  = *(const short8*)(ax + kc * 32);
          short8 ao  = *(const short8*)(ax + (kc + 1) * 32);
          short8 b0e = *(const short8*)(smB + (size_t)(32 + kc) * 512 + lane * 8);
          short8 b1e = *(const short8*)(smB + (size_t)(96 + kc) * 512 + lane * 8);
          short8 b0o = *(const short8*)(smB + (size_t)(33 + kc) * 512 + lane * 8);
          short8 b1o = *(const short8*)(smB + (size_t)(97 + kc) * 512 + lane * 8);
          x0e = MFMA16(ae, b0e, x0e); x1e = MFMA16(ae, b1e, x1e);
          x0o = MFMA16(ao, b0o, x0o); x1o = MFMA16(ao, b1o, x1o);
        }
      }

      // ---- wait for h_t: one lane per flag, 4 lines total ----
      if (tid < NSW) {
        const unsigned* fp = hflags + tid;
        while (ld_u32_mall(fp) < (unsigned)t) { }
      }
      __syncthreads();

      if (MODE == 0) {   // x_t staged by step wgs last step (bypass)
#pragma unroll
        for (int kc = 0; kc < 32; kc += 2) {
          short8 ae  = ld_a16_mall(xA + rowoff + kc * 32);
          short8 ao  = ld_a16_mall(xA + rowoff + (kc + 1) * 32);
          short8 b0e = *(const short8*)(smB + (size_t)(32 + kc) * 512 + lane * 8);
          short8 b1e = *(const short8*)(smB + (size_t)(96 + kc) * 512 + lane * 8);
          short8 b0o = *(const short8*)(smB + (size_t)(33 + kc) * 512 + lane * 8);
          short8 b1o = *(const short8*)(smB + (size_t)(97 + kc) * 512 + lane * 8);
          x0e = MFMA16(ae, b0e, x0e); x1e = MFMA16(ae, b1e, x1e);
          x0o = MFMA16(ao, b0o, x0o); x1o = MFMA16(ao, b1o, x1o);
        }
      }

      // ---- h-part: prefetch all A-fragments, then MFMA ----
      short8 aH[32];
      if (MODE == 2) {
        const unsigned short* ah = hA + (size_t)t * BHID + rowoff;
#pragma unroll
        for (int kc = 0; kc < 32; ++kc)
          aH[kc] = *(const short8*)(ah + kc * 32);     // cached dwordx4
      } else {
#pragma unroll
        for (int kc = 0; kc < 32; ++kc)
          aH[kc] = ld_a16_mall(hA + rowoff + kc * 32); // bypass
      }

      floatx4 h0e = z, h1e = z, h0o = z, h1o = z;
#pragma unroll
      for (int kc = 0; kc < 32; kc += 2) {
        short8 b0e = *(const short8*)(smB + (size_t)kc * 512 + lane * 8);
        short8 b1e = *(const short8*)(smB + (size_t)(64 + kc) * 512 + lane * 8);
        short8 b0o = *(const short8*)(smB + (size_t)(kc + 1) * 512 + lane * 8);
        short8 b1o = *(const short8*)(smB + (size_t)(65 + kc) * 512 + lane * 8);
        h0e = MFMA16(aH[kc],     b0e, h0e); h1e = MFMA16(aH[kc],     b1e, h1e);
        h0o = MFMA16(aH[kc + 1], b0o, h0o); h1o = MFMA16(aH[kc + 1], b1o, h1o);
      }

      // C/D layout (m89-verified): col = l16 (in tile), row = quad*4 + r
#pragma unroll
      for (int r = 0; r < 4; ++r) {
        int m = wave * 16 + quad * 4 + r;
        float* gm = gates + (size_t)m * GDIM + n0 + l16;
        st_u32_mall(gm,      __float_as_uint((h0e[r] + h0o[r]) + (x0e[r] + x0o[r])));
        st_u32_mall(gm + 16, __float_as_uint((h1e[r] + h1o[r]) + (x1e[r] + x1o[r])));
      }
      asm volatile("s_waitcnt vmcnt(0)" ::: "memory");  // gates at MALL
      __syncthreads();
      if (tid == 0)
        st_u32_mall(gflags + wg, (unsigned)(t + 1));
    }
  } else {
    // =========================== step/LN wg ==============================
    const int b = wg - NGW;
    const int j = tid * 4;

    float cc[4], wcf[4], wci[4], wco[4];
    float gf4[4], gi4[4], gg4[4], go4[4], gc4[4], bc4[4];
    float bf4[4], bi4[4], bg4[4], bo4[4];
    LOAD4(cc,  c_ws + (size_t)b * HID + j);
    LOAD4(wcf, w_ch + j);
    LOAD4(wci, w_ch + HID + j);
    LOAD4(wco, w_ch + 2 * HID + j);
    LOAD4(gf4, gamma_f + j); LOAD4(gi4, gamma_i + j);
    LOAD4(gg4, gamma_g + j); LOAD4(go4, gamma_o + j);
    LOAD4(gc4, gamma_c + j); LOAD4(bc4, beta_c + j);
    LOAD4(bf4, bias + j);           LOAD4(bi4, bias + HID + j);
    LOAD4(bg4, bias + 2 * HID + j); LOAD4(bo4, bias + 3 * HID + j);
    const float invH = 1.0f / (float)HID;

    for (int t = 0; t < T_STEPS; ++t) {
      const int has_next = (t + 1 < T_STEPS);
      float4 xv;
      if (MODE == 0 && has_next)
        xv = *(const float4*)(input + (size_t)(t + 1) * BHID + (size_t)b * HID + j);

      // ---- wait for all 128 gate tiles: one lane per flag, 8 lines ----
      if (tid < NGW) {
        const unsigned* fp = gflags + tid;
        while (ld_u32_mall(fp) < (unsigned)(t + 1)) { }
      }
      __syncthreads();

      float fh[4], ih[4], gh[4], oh[4];
      const float* grow = gates + (size_t)b * GDIM;
      ld4f_mall(fh, grow + j);
      ld4f_mall(ih, grow + HID + j);
      ld4f_mall(gh, grow + 2 * HID + j);
      ld4f_mall(oh, grow + 3 * HID + j);

      if (MODE == 0 && has_next)
        st4h_mall(xbuf + (size_t)b * HID + j, xv.x, xv.y, xv.z, xv.w);

      float af[4], ai[4], ag[4];
      float s[6] = {0, 0, 0, 0, 0, 0};
#pragma unroll
      for (int r = 0; r < 4; ++r) {
        af[r] = fh[r] + wcf[r] * cc[r];
        ai[r] = ih[r] + wci[r] * cc[r];
        ag[r] = gh[r];
        s[0] += af[r]; s[1] += af[r] * af[r];
        s[2] += ai[r]; s[3] += ai[r] * ai[r];
        s[4] += ag[r]; s[5] += ag[r] * ag[r];
      }
      block_reduce<6>(s, sm, tid);
      float mu_f = s[0] * invH, is_f = rsqrtf(s[1] * invH - mu_f * mu_f + 1e-5f);
      float mu_i = s[2] * invH, is_i = rsqrtf(s[3] * invH - mu_i * mu_i + 1e-5f);
      float mu_g = s[4] * invH, is_g = rsqrtf(s[5] * invH - mu_g * mu_g + 1e-5f);

      float cn[4], ao[4];
      float s2[4] = {0, 0, 0, 0};
#pragma unroll
      for (int r = 0; r < 4; ++r) {
        float f = sigmoid_((af[r] - mu_f) * is_f * gf4[r] + bf4[r]);
        float i = sigmoid_((ai[r] - mu_i) * is_i * gi4[r] + bi4[r]);
        float g = tanh_((ag[r] - mu_g) * is_g * gg4[r] + bg4[r]);
        cn[r] = f * cc[r] + i * g;
        ao[r] = oh[r] + wco[r] * cn[r];
        s2[0] += cn[r]; s2[1] += cn[r] * cn[r];
        s2[2] += ao[r]; s2[3] += ao[r] * ao[r];
      }
#pragma unroll
      for (int r = 0; r < 4; ++r) cc[r] = cn[r];   // c lives in registers

      block_reduce<4>(s2, sm + 24, tid);
      float mu_c = s2[0] * invH, is_c = rsqrtf(s2[1] * invH - mu_c * mu_c + 1e-5f);
      float mu_o = s2[2] * invH, is_o = rsqrtf(s2[3] * invH - mu_o * mu_o + 1e-5f);

      float h4[4];
#pragma unroll
      for (int r = 0; r < 4; ++r) {
        float cl = (cn[r] - mu_c) * is_c * gc4[r] + bc4[r];
        float o  = sigmoid_((ao[r] - mu_o) * is_o * go4[r] + bo4[r]);
        h4[r] = o * tanh_(cl);
      }
      { float4 tt; tt.x = h4[0]; tt.y = h4[1]; tt.z = h4[2]; tt.w = h4[3];
        *(float4*)(out + (size_t)t * BHID + (size_t)b * HID + j) = tt; }
      if (has_next) {
        unsigned short* hd = (MODE == 2)
            ? hA + (size_t)(t + 1) * BHID + (size_t)b * HID + j
            : hA + (size_t)b * HID + j;
        st4h_mall(hd, h4[0], h4[1], h4[2], h4[3]);
      }

      asm volatile("s_waitcnt vmcnt(0)" ::: "memory");  // h (and x) at MALL
      __syncthreads();
      if (tid == 0)
        st_u32_mall(hflags + b, (unsigned)(t + 1));
    }

    { float4 tt; tt.x = cc[0]; tt.y = cc[1]; tt.z = cc[2]; tt.w = cc[3];
      *(float4*)(c_ws + (size_t)b * HID + j) = tt; }
  }
}

// ---------------------------------------------------------------------------
extern "C" void kernel_launch(void* const* d_in, const int* in_sizes, int n_in,
                              void* d_out, int out_size, void* d_ws, size_t ws_size,
                              hipStream_t stream) {
  (void)in_sizes; (void)n_in; (void)out_size;
  const float* input   = (const float*)d_in[0];
  const float* hidden  = (const float*)d_in[1];
  const float* cell    = (const float*)d_in[2];
  const float* w_ih    = (const float*)d_in[3];
  const float* w_hh    = (const float*)d_in[4];
  const float* w_ch    = (const float*)d_in[5];
  const float* bias    = (const float*)d_in[6];
  const float* gamma_f = (const float*)d_in[7];
  const float* gamma_i = (const float*)d_in[8];
  const float* gamma_g = (const float*)d_in[9];
  const float* gamma_o = (const float*)d_in[10];
  const float* gamma_c = (const float*)d_in[11];
  const float* beta_c  = (const float*)d_in[12];
  float* out = (float*)d_out;

  const size_t SZ_WCAT = (size_t)GDIM * KDIM * sizeof(unsigned short);    // 16 MB
  const size_t SZ_XALL = (size_t)T_STEPS * BHID * sizeof(unsigned short); // 64 MB
  const size_t SZ_HPOOL= (size_t)T_STEPS * BHID * sizeof(unsigned short); // 64 MB
  const size_t SZ_BUF  = (size_t)BHID * sizeof(unsigned short);           // 128 KB
  const size_t SZ_GATE = (size_t)BATCH * GDIM * sizeof(float);            // 1 MB
  const size_t SZ_VEC  = (size_t)BHID * sizeof(float);                    // 256 KB
  const size_t SZ_FLAG = 16384;
  const size_t TAIL = SZ_GATE + SZ_VEC + SZ_FLAG;
  const size_t NEED2 = SZ_WCAT + SZ_XALL + SZ_HPOOL + TAIL;
  const size_t NEED1 = SZ_WCAT + SZ_XALL + SZ_BUF + TAIL;

  char* p = (char*)d_ws;
  unsigned short* wcat = (unsigned short*)p;  p += SZ_WCAT;
  int mode = (ws_size >= NEED2) ? 2 : (ws_size >= NEED1) ? 1 : 0;

  unsigned short *xA, *xbuf, *hA;
  if (mode >= 1) {
    xA = (unsigned short*)p; p += SZ_XALL; xbuf = xA;
    hA = (unsigned short*)p; p += (mode == 2) ? SZ_HPOOL : SZ_BUF;
  } else {
    xA = (unsigned short*)p; p += SZ_BUF;  xbuf = xA;
    hA = (unsigned short*)p; p += SZ_BUF;
  }
  float* gates = (float*)p;  p += SZ_GATE;
  float* c_ws  = (float*)p;  p += SZ_VEC;
  unsigned* syncp = (unsigned*)p;

  cvt_w_kernel<<<(GDIM * KDIM / 4) / 256, 256, 0, stream>>>(w_hh, w_ih, wcat);
  if (mode >= 1)
    cvt_x_kernel<<<((size_t)T_STEPS * BHID / 8) / 256, 256, 0, stream>>>(input, xA);
  init_kernel<<<BATCH, 256, 0, stream>>>(hidden, input, cell, hA, xA, c_ws);
  hipMemsetAsync(syncp, 0, SZ_FLAG, stream);   // flags zero on every replay

  if (mode == 2)
    lstm_persist<2><<<NGW + NSW, 256, 0, stream>>>(
        wcat, input, xA, xbuf, gates, c_ws, w_ch, bias, gamma_f, gamma_i,
        gamma_g, gamma_o, gamma_c, beta_c, out, hA, syncp);
  else if (mode == 1)
    lstm_persist<1><<<NGW + NSW, 256, 0, stream>>>(
        wcat, input, xA, xbuf, gates, c_ws, w_ch, bias, gamma_f, gamma_i,
        gamma_g, gamma_o, gamma_c, beta_c, out, hA, syncp);
  else
    lstm_persist<0><<<NGW + NSW, 256, 0, stream>>>(
        wcat, input, xA, xbuf, gates, c_ws, w_ch, bias, gamma_f, gamma_i,
        gamma_g, gamma_o, gamma_c, beta_c, out, hA, syncp);

  const size_t OUT0 = (size_t)T_STEPS * BHID;
  hipMemcpyAsync(out + OUT0, out + (OUT0 - BHID),
                 (size_t)BHID * sizeof(float), hipMemcpyDeviceToDevice, stream);
  hipMemcpyAsync(out + OUT0 + BHID, c_ws,
                 (size_t)BHID * sizeof(float), hipMemcpyDeviceToDevice, stream);
}